// Round 2
// baseline (1915.737 us; speedup 1.0000x reference)
//
#include <hip/hip_runtime.h>
#include <hip/hip_bf16.h>
#include <math.h>

// ---------------- workspace layout (element offsets into float* ws) --------
static constexpr size_t SIMS_OFF   = 0;         // 500000 float
static constexpr size_t Q_OFF      = 500736;    // 512 float
static constexpr size_t QN_OFF     = 501248;    // 512 float
static constexpr size_t HIST_OFF   = 501760;    // 4096 uint
static constexpr size_t COUNT_OFF  = 505856;    // 16 uint (count at [0])
static constexpr size_t THRESH_OFF = 505872;    // 16 float
static constexpr size_t CANDV_OFF  = 505888;    // 8192 float
static constexpr size_t CANDI_OFF  = 514080;    // 8192 int
static constexpr size_t SELI_OFF   = 522272;    // 32 int
static constexpr size_t SELV_OFF   = 522304;    // 32 float
static constexpr size_t COMB_OFF   = 522336;    // 32*1024 float (16B aligned)
static constexpr size_t H_OFF      = 555104;    // 32*512 float

static constexpr int D_LAT   = 512;
static constexpr int D_QRY   = 768;
static constexpr int NBUCKET = 4096;
static constexpr int CAND_CAP= 8192;
static constexpr int LDS_CAP = 4096;
static constexpr int K2      = 32;   // 2k
static constexpr int K1      = 16;   // k

// ---------------- 1a. query projection: q = Wp @ query + bp -----------------
// 128 blocks x 256 threads = 512 waves, one wave per output row
__global__ __launch_bounds__(256) void k_proj(
    const float* __restrict__ Wp, const float* __restrict__ query,
    const float* __restrict__ bp, float* __restrict__ q) {
  const int lane = threadIdx.x & 63;
  const int row  = blockIdx.x * 4 + (threadIdx.x >> 6);   // 0..511
  const float4* q4 = (const float4*)query;
  float4 qq0 = q4[lane*3+0], qq1 = q4[lane*3+1], qq2 = q4[lane*3+2];
  const float4* w4 = (const float4*)(Wp + (size_t)row * D_QRY);
  float4 w0 = w4[lane*3+0], w1 = w4[lane*3+1], w2 = w4[lane*3+2];
  float acc = w0.x*qq0.x + w0.y*qq0.y + w0.z*qq0.z + w0.w*qq0.w
            + w1.x*qq1.x + w1.y*qq1.y + w1.z*qq1.z + w1.w*qq1.w
            + w2.x*qq2.x + w2.y*qq2.y + w2.z*qq2.z + w2.w*qq2.w;
#pragma unroll
  for (int off = 32; off; off >>= 1) acc += __shfl_xor(acc, off, 64);
  if (lane == 0) q[row] = acc + bp[row];
}

// ---------------- 1b. normalize: qn = q / (||q|| + 1e-8) --------------------
__global__ __launch_bounds__(512) void k_norm(
    const float* __restrict__ q, float* __restrict__ qn) {
  __shared__ float s_red[512];
  int tid = threadIdx.x;
  float v = q[tid];
  s_red[tid] = v * v;
  __syncthreads();
  for (int s = 256; s > 0; s >>= 1) {
    if (tid < s) s_red[tid] += s_red[tid + s];
    __syncthreads();
  }
  qn[tid] = v / (sqrtf(s_red[0]) + 1e-8f);
}

// ---------------- 2. cosine sims + global histogram -------------------------
// one wave per row; lane covers 8 floats (2 float4) of the 512-dim row
__global__ __launch_bounds__(256) void k_sims(
    const float* __restrict__ mem, const float* __restrict__ qn,
    float* __restrict__ sims, unsigned* __restrict__ ghist, int nrows) {
  const int lane   = threadIdx.x & 63;
  const int wave   = (blockIdx.x * 256 + threadIdx.x) >> 6;
  const int nwaves = (gridDim.x * 256) >> 6;

  const float4* qn4 = (const float4*)qn;
  float4 qa = qn4[lane*2], qb = qn4[lane*2+1];

  for (int row = wave; row < nrows; row += nwaves) {
    const float4* m4 = (const float4*)(mem + (size_t)row * D_LAT);
    float4 a = m4[lane*2], b = m4[lane*2+1];
    float dot = a.x*qa.x + a.y*qa.y + a.z*qa.z + a.w*qa.w
              + b.x*qb.x + b.y*qb.y + b.z*qb.z + b.w*qb.w;
    float ss  = a.x*a.x + a.y*a.y + a.z*a.z + a.w*a.w
              + b.x*b.x + b.y*b.y + b.z*b.z + b.w*b.w;
#pragma unroll
    for (int off = 32; off; off >>= 1) {
      dot += __shfl_xor(dot, off, 64);
      ss  += __shfl_xor(ss,  off, 64);
    }
    if (lane == 0) {
      float s = dot / (sqrtf(ss) + 1e-8f);
      sims[row] = s;
      int bkt = (int)((s + 1.0f) * 2048.0f);
      bkt = bkt < 0 ? 0 : (bkt > NBUCKET-1 ? NBUCKET-1 : bkt);
      atomicAdd(&ghist[bkt], 1u);
    }
  }
}

// ---------------- 3. find value threshold covering top-32 (one wave) --------
// lane l owns bins [l*64, (l+1)*64); shuffle suffix-scan locates the cutoff
__global__ __launch_bounds__(64) void k_thresh(
    const unsigned* __restrict__ ghist, float* __restrict__ thresh) {
  __shared__ unsigned s_h[NBUCKET];
  const int lane = threadIdx.x;
  unsigned csum = 0;
#pragma unroll 8
  for (int j = 0; j < 64; ++j) {
    unsigned v = ghist[lane * 64 + j];
    s_h[lane * 64 + j] = v;         // same-lane read later, no sync needed
    csum += v;
  }
  // inclusive suffix sum across lanes: suf[l] = sum_{m>=l} csum[m]
  unsigned suf = csum;
#pragma unroll
  for (int off = 1; off < 64; off <<= 1) {
    unsigned t = __shfl_down(suf, off, 64);
    if (lane + off < 64) suf += t;
  }
  unsigned above = suf - csum;      // count strictly above this chunk
  if (lane == 0 && suf < (unsigned)K2) thresh[0] = -2.0f;  // degenerate: take all
  if (above < (unsigned)K2 && suf >= (unsigned)K2) {       // unique lane
    unsigned cum = above;
    int b = lane * 64;
    for (int j = 63; j >= 0; --j) {
      cum += s_h[lane * 64 + j];
      if (cum >= (unsigned)K2) { b = lane * 64 + j; break; }
    }
    thresh[0] = (float)b * (1.0f / 2048.0f) - 1.0f - 1e-6f;
  }
}

// ---------------- 4. collect candidates >= threshold ------------------------
__global__ __launch_bounds__(256) void k_collect(
    const float* __restrict__ sims, const float* __restrict__ thresh,
    float* __restrict__ cv, int* __restrict__ ci, unsigned* __restrict__ count, int n) {
  float t = thresh[0];
  int stride = gridDim.x * 256;
  for (int i = blockIdx.x * 256 + threadIdx.x; i < n; i += stride) {
    float v = sims[i];
    if (v >= t) {
      unsigned p = atomicAdd(count, 1u);
      if (p < (unsigned)CAND_CAP) { cv[p] = v; ci[p] = i; }
    }
  }
}

// ---------------- 5. top-32 select (jax tie-break) + gather combined --------
__global__ __launch_bounds__(256) void k_select(
    const float* __restrict__ cv, const int* __restrict__ ci,
    const unsigned* __restrict__ count, const float* __restrict__ q,
    const float* __restrict__ mem, int* __restrict__ seli,
    float* __restrict__ selv, float* __restrict__ comb) {
  __shared__ float s_v[LDS_CAP];
  __shared__ int   s_i[LDS_CAP];
  __shared__ int   s_idx[K2];
  __shared__ float s_val[K2];
  int n = (int)(*count);
  if (n > CAND_CAP) n = CAND_CAP;
  const bool lds_ok = (n <= LDS_CAP);
  if (lds_ok) {
    for (int i = threadIdx.x; i < n; i += 256) { s_v[i] = cv[i]; s_i[i] = ci[i]; }
  }
  __syncthreads();
  if (threadIdx.x == 0) {
    // successive-max selection: total order = (val desc, idx asc)
    float pv = 1e30f; int pi = -1;
    for (int s = 0; s < K2; ++s) {
      float bv = -1e30f; int bi = 0x7fffffff;
      for (int j = 0; j < n; ++j) {
        float v  = lds_ok ? s_v[j] : cv[j];
        int   id = lds_ok ? s_i[j] : ci[j];
        if (v > pv || (v == pv && id <= pi)) continue;   // not after prev pick
        if (v > bv || (v == bv && id < bi)) { bv = v; bi = id; }
      }
      s_val[s] = bv; s_idx[s] = bi;
      pv = bv; pi = bi;
    }
  }
  __syncthreads();
  if (threadIdx.x < K2) { seli[threadIdx.x] = s_idx[threadIdx.x]; selv[threadIdx.x] = s_val[threadIdx.x]; }
  // combined[c][0:512] = q ; combined[c][512:1024] = memory[idx_c]
  for (int t = threadIdx.x; t < K2 * 2 * D_LAT; t += 256) {
    int c = t >> 10, j = t & 1023;
    comb[t] = (j < D_LAT) ? q[j] : mem[(size_t)s_idx[c] * D_LAT + (j - D_LAT)];
  }
}

// ---------------- 6. rerank MLP layer 1: h = relu(comb @ W1^T + b1) ---------
// 16384 outputs (c,i); thread t: c = t&31, i = t>>5
__global__ __launch_bounds__(256) void k_mlp1(
    const float* __restrict__ comb, const float* __restrict__ W1,
    const float* __restrict__ b1, float* __restrict__ h) {
  int t = blockIdx.x * 256 + threadIdx.x;
  int c = t & 31, i = t >> 5;
  const float4* w4 = (const float4*)(W1 + (size_t)i * (2*D_LAT));
  const float4* c4 = (const float4*)(comb + (size_t)c * (2*D_LAT));
  float acc = 0.f;
#pragma unroll 8
  for (int j = 0; j < (2*D_LAT)/4; ++j) {
    float4 w = w4[j], x = c4[j];
    acc += w.x*x.x + w.y*x.y + w.z*x.z + w.w*x.w;
  }
  acc += b1[i];
  h[(size_t)c * D_LAT + i] = fmaxf(acc, 0.f);
}

// ---------------- 7. scores + top-16 + write output -------------------------
// 8 threads per candidate for the 512-dot, LDS reduce, serial top-16
__global__ __launch_bounds__(256) void k_final(
    const float* __restrict__ h, const float* __restrict__ W2,
    const float* __restrict__ b2, const int* __restrict__ seli,
    float* __restrict__ out) {
  __shared__ float part[256];
  __shared__ float sc[K2];
  const int t = threadIdx.x;
  const int c = t >> 3, p = t & 7;
  const float4* hr = (const float4*)(h + (size_t)c * D_LAT + p * 64);
  const float4* w  = (const float4*)(W2 + p * 64);
  float acc = 0.f;
#pragma unroll
  for (int j = 0; j < 16; ++j) {
    float4 a = hr[j], b = w[j];
    acc += a.x*b.x + a.y*b.y + a.z*b.z + a.w*b.w;
  }
  part[t] = acc;
  __syncthreads();
  if (p == 0) {
    float s = part[t]+part[t+1]+part[t+2]+part[t+3]+part[t+4]+part[t+5]+part[t+6]+part[t+7];
    sc[c] = s + b2[0];
  }
  __syncthreads();
  if (t == 0) {
    float pv = 1e30f; int pc = -1;
    for (int s = 0; s < K1; ++s) {
      float bv = -1e30f; int bc = 0;
      for (int c2 = 0; c2 < K2; ++c2) {
        float v = sc[c2];
        if (v > pv || (v == pv && c2 <= pc)) continue;
        if (v > bv) { bv = v; bc = c2; }     // c2 ascending: ties keep lower
      }
      out[s]      = bv;
      out[K1 + s] = (float)seli[bc];         // indices written as float32
      pv = bv; pc = bc;
    }
  }
}

// ---------------- launch -----------------------------------------------------
extern "C" void kernel_launch(void* const* d_in, const int* in_sizes, int n_in,
                              void* d_out, int out_size, void* d_ws, size_t ws_size,
                              hipStream_t stream) {
  (void)n_in; (void)out_size; (void)ws_size;
  const float* query  = (const float*)d_in[0];
  const float* memory = (const float*)d_in[1];
  const float* Wp     = (const float*)d_in[2];
  const float* bp     = (const float*)d_in[3];
  const float* W1     = (const float*)d_in[4];
  const float* b1     = (const float*)d_in[5];
  const float* W2     = (const float*)d_in[6];
  const float* b2     = (const float*)d_in[7];
  const int nrows = in_sizes[1] / D_LAT;   // 500000

  float*    ws    = (float*)d_ws;
  float*    sims  = ws + SIMS_OFF;
  float*    q     = ws + Q_OFF;
  float*    qn    = ws + QN_OFF;
  unsigned* hist  = (unsigned*)(ws + HIST_OFF);
  unsigned* count = (unsigned*)(ws + COUNT_OFF);
  float*    thr   = ws + THRESH_OFF;
  float*    candv = ws + CANDV_OFF;
  int*      candi = (int*)(ws + CANDI_OFF);
  int*      seli  = (int*)(ws + SELI_OFF);
  float*    selv  = ws + SELV_OFF;
  float*    comb  = ws + COMB_OFF;
  float*    h     = ws + H_OFF;
  float*    out   = (float*)d_out;

  hipMemsetAsync(hist, 0, (NBUCKET + 16) * sizeof(unsigned), stream);  // hist + count
  k_proj   <<<128,  256, 0, stream>>>(Wp, query, bp, q);
  k_norm   <<<1,    512, 0, stream>>>(q, qn);
  k_sims   <<<4096, 256, 0, stream>>>(memory, qn, sims, hist, nrows);
  k_thresh <<<1,     64, 0, stream>>>(hist, thr);
  k_collect<<<256,  256, 0, stream>>>(sims, thr, candv, candi, count, nrows);
  k_select <<<1,    256, 0, stream>>>(candv, candi, count, q, memory, seli, selv, comb);
  k_mlp1   <<<64,   256, 0, stream>>>(comb, W1, b1, h);
  k_final  <<<1,    256, 0, stream>>>(h, W2, b2, seli, out);
}